// Round 8
// baseline (246.492 us; speedup 1.0000x reference)
//
#include <hip/hip_runtime.h>
#include <math.h>
#include <stdint.h>

// GraphTransformerLayer on MI355X (gfx950).
// B=8, N=1024, D=512, H=8, Dh=64, F=2048.
// Round 8: eadj = mask?exp(adj):0 bf16 table factored OUT of the exponent
//          (p = eadj * exp(s - C), C = |q'|*kmax); attn_ctx walks full k,
//          normalizes in-kernel (k_attn_fin removed), eadj loads pipelined
//          cross-tile, setprio around MFMA clusters.

using bf16_t = __bf16;
typedef __attribute__((__ext_vector_type__(8))) __bf16 bf16x8;
typedef __attribute__((__ext_vector_type__(4))) __bf16 bf16x4;
typedef __attribute__((__ext_vector_type__(4))) float  f32x4;

#define DEVI __device__ __forceinline__

DEVI f32x4 mfma16(bf16x8 a, bf16x8 b, f32x4 c) {
  return __builtin_amdgcn_mfma_f32_16x16x32_bf16(a, b, c, 0, 0, 0);
}

// async global->LDS, 16B per lane. dest = wave-uniform base (+ lane*16 by HW).
DEVI void gload_lds16(const void* g, void* l) {
  __builtin_amdgcn_global_load_lds(
      (const __attribute__((address_space(1))) uint32_t*)g,
      (__attribute__((address_space(3))) uint32_t*)l, 16, 0, 0);
}

#define EPSC  (1e-5f)

// ---------------- f32 -> bf16 convert (vector4) ----------------
__global__ __launch_bounds__(256) void k_cvt(const float* __restrict__ in,
                                             bf16_t* __restrict__ out, int n4) {
  int i = blockIdx.x * 256 + threadIdx.x;
  if (i < n4) {
    float4 v = ((const float4*)in)[i];
    bf16x4 o = { (__bf16)v.x, (__bf16)v.y, (__bf16)v.z, (__bf16)v.w };
    ((bf16x4*)out)[i] = o;
  }
}

// ---------------- fused weight converts ----------------
__global__ __launch_bounds__(256) void k_cvtw(const float* __restrict__ wq,
                                              const float* __restrict__ wk,
                                              const float* __restrict__ wv,
                                              const float* __restrict__ wo,
                                              const float* __restrict__ w1,
                                              const float* __restrict__ w2,
                                              bf16_t* __restrict__ owq,
                                              bf16_t* __restrict__ owk,
                                              bf16_t* __restrict__ owv,
                                              bf16_t* __restrict__ owo,
                                              bf16_t* __restrict__ ow1,
                                              bf16_t* __restrict__ ow2) {
  int blk = blockIdx.x;
  const float* src; bf16_t* dst; int base;
  if      (blk < 256)  { src = wq; dst = owq; base = blk; }
  else if (blk < 512)  { src = wk; dst = owk; base = blk - 256; }
  else if (blk < 768)  { src = wv; dst = owv; base = blk - 512; }
  else if (blk < 1024) { src = wo; dst = owo; base = blk - 768; }
  else if (blk < 2048) { src = w1; dst = ow1; base = blk - 1024; }
  else                 { src = w2; dst = ow2; base = blk - 2048; }
  int i = base * 256 + threadIdx.x;
  float4 v = ((const float4*)src)[i];
  bf16x4 o = { (__bf16)v.x, (__bf16)v.y, (__bf16)v.z, (__bf16)v.w };
  ((bf16x4*)dst)[i] = o;
}

// ---------------- eadj = mask ? exp(adj) : 0  (bf16 table) ----------------
__global__ __launch_bounds__(256) void k_prep(const float* __restrict__ adj,
                                              const int* __restrict__ msk,
                                              bf16_t* __restrict__ eadj) {
  int row  = blockIdx.x * 4 + (threadIdx.x >> 6);
  int lane = threadIdx.x & 63;
  for (int i = 0; i < 16; i++) {
    int c = lane + 64 * i;
    size_t idx = (size_t)row * 1024 + c;
    float a = adj[idx];
    bool valid = (msk[idx] != 0);
    eadj[idx] = valid ? (__bf16)__expf(a) : (__bf16)0.f;
  }
}

// ---------------- tiled GEMM: C[8192 x N] = A[8192 x K] @ B[N x K]^T ----------------
// 128x128 tile, 4 waves (2x2), each wave 64x64 (4x4 fragments). BK=32.
// Double-buffered global_load_lds staging, 16B-block XOR swizzle (blk ^= row&3).
template<int EPI>
__global__ __launch_bounds__(256) void k_gemm(const bf16_t* __restrict__ A,
                                              const bf16_t* __restrict__ B,
                                              int K, int nbx,
                                              const float* __restrict__ bias,
                                              bf16_t* __restrict__ outb,
                                              float* __restrict__ outf,
                                              int out_ncols) {
  __shared__ bf16_t lA[2][4096];
  __shared__ bf16_t lB[2][4096];
  int bid = blockIdx.x;
  int nb = bid % nbx, mb = bid / nbx;
  int tid = threadIdx.x, wid = tid >> 6, lane = tid & 63;
  int l16 = lane & 15, g = lane >> 4;
  int wr = wid >> 1, wc = wid & 1;
  int rowbase = mb * 128, c0 = nb * 128;

  int dA0 = wid * 2048 + lane * 16;
  int rA0 = dA0 >> 6;
  int cbA = ((dA0 >> 4) & 3) ^ (rA0 & 3);
  const bf16_t* Asrc0 = A + (size_t)(rowbase + rA0) * K + cbA * 8;
  const bf16_t* Asrc1 = A + (size_t)(rowbase + rA0 + 16) * K + cbA * 8;
  const bf16_t* Bsrc0 = B + (size_t)(c0 + rA0) * K + cbA * 8;
  const bf16_t* Bsrc1 = B + (size_t)(c0 + rA0 + 16) * K + cbA * 8;

  f32x4 acc[4][4];
#pragma unroll
  for (int m = 0; m < 4; m++)
#pragma unroll
    for (int n = 0; n < 4; n++) acc[m][n] = (f32x4){0.f, 0.f, 0.f, 0.f};

  gload_lds16(Asrc0, (char*)&lA[0][0] + wid * 2048);
  gload_lds16(Asrc1, (char*)&lA[0][0] + wid * 2048 + 1024);
  gload_lds16(Bsrc0, (char*)&lB[0][0] + wid * 2048);
  gload_lds16(Bsrc1, (char*)&lB[0][0] + wid * 2048 + 1024);
  __syncthreads();

  for (int k0 = 0; k0 < K; k0 += 32) {
    int buf = (k0 >> 5) & 1;
    if (k0 + 32 < K) {
      gload_lds16(Asrc0 + k0 + 32, (char*)&lA[buf ^ 1][0] + wid * 2048);
      gload_lds16(Asrc1 + k0 + 32, (char*)&lA[buf ^ 1][0] + wid * 2048 + 1024);
      gload_lds16(Bsrc0 + k0 + 32, (char*)&lB[buf ^ 1][0] + wid * 2048);
      gload_lds16(Bsrc1 + k0 + 32, (char*)&lB[buf ^ 1][0] + wid * 2048 + 1024);
    }
    const char* cA = (const char*)&lA[buf][0];
    const char* cB = (const char*)&lB[buf][0];
    bf16x8 af[4], bq[4];
#pragma unroll
    for (int m = 0; m < 4; m++) {
      int row = wr * 64 + m * 16 + l16;
      af[m] = *(const bf16x8*)(cA + row * 64 + ((g ^ (row & 3)) << 4));
    }
#pragma unroll
    for (int n = 0; n < 4; n++) {
      int row = wc * 64 + n * 16 + l16;
      bq[n] = *(const bf16x8*)(cB + row * 64 + ((g ^ (row & 3)) << 4));
    }
#pragma unroll
    for (int m = 0; m < 4; m++)
#pragma unroll
      for (int n = 0; n < 4; n++) acc[m][n] = mfma16(af[m], bq[n], acc[m][n]);
    __syncthreads();
  }

  int which = c0 / out_ncols;
  int cloc0 = c0 - which * out_ncols;
  size_t obase = (size_t)which * 8192 * out_ncols;
  float osc = (EPI == 0 && which == 0) ? 0.125f : 1.0f;  // q pre-scale
#pragma unroll
  for (int n = 0; n < 4; n++) {
    int col = cloc0 + wc * 64 + n * 16 + l16;
    float bv = (EPI >= 1 && bias) ? bias[col] : 0.f;
#pragma unroll
    for (int m = 0; m < 4; m++)
#pragma unroll
      for (int j = 0; j < 4; j++) {
        int row = rowbase + wr * 64 + m * 16 + g * 4 + j;
        float v = acc[m][n][j] + bv;
        size_t idx = obase + (size_t)row * out_ncols + col;
        if (EPI == 1) outb[idx] = (__bf16)fmaxf(v, 0.f);
        else if (EPI == 0) outb[idx] = (__bf16)(v * osc);
        else outf[idx] = v;
      }
  }
}

// ---------------- residual + LayerNorm (memory-bound): rows of 512 ----------------
__global__ __launch_bounds__(256) void k_resln(const float* __restrict__ gin,
                                               const float* __restrict__ residf,
                                               const bf16_t* __restrict__ residb,
                                               const float* __restrict__ gam,
                                               const float* __restrict__ bet,
                                               float* __restrict__ outf,
                                               bf16_t* __restrict__ outb) {
  int row = blockIdx.x * 4 + (threadIdx.x >> 6);
  int lane = threadIdx.x & 63;
  const float* gp = gin + (size_t)row * 512;
  float4 a0 = ((const float4*)gp)[lane];
  float4 a1 = ((const float4*)gp)[lane + 64];
  if (residf) {
    const float* rp = residf + (size_t)row * 512;
    float4 r0 = ((const float4*)rp)[lane];
    float4 r1 = ((const float4*)rp)[lane + 64];
    a0.x += r0.x; a0.y += r0.y; a0.z += r0.z; a0.w += r0.w;
    a1.x += r1.x; a1.y += r1.y; a1.z += r1.z; a1.w += r1.w;
  } else {
    const bf16_t* rp = residb + (size_t)row * 512;
    bf16x4 r0 = ((const bf16x4*)rp)[lane];
    bf16x4 r1 = ((const bf16x4*)rp)[lane + 64];
    a0.x += (float)r0[0]; a0.y += (float)r0[1]; a0.z += (float)r0[2]; a0.w += (float)r0[3];
    a1.x += (float)r1[0]; a1.y += (float)r1[1]; a1.z += (float)r1[2]; a1.w += (float)r1[3];
  }
  float s = a0.x + a0.y + a0.z + a0.w + a1.x + a1.y + a1.z + a1.w;
  for (int off = 1; off < 64; off <<= 1) s += __shfl_xor(s, off);
  float mu = s * (1.f / 512.f);
  float sq = (a0.x - mu) * (a0.x - mu) + (a0.y - mu) * (a0.y - mu) +
             (a0.z - mu) * (a0.z - mu) + (a0.w - mu) * (a0.w - mu) +
             (a1.x - mu) * (a1.x - mu) + (a1.y - mu) * (a1.y - mu) +
             (a1.z - mu) * (a1.z - mu) + (a1.w - mu) * (a1.w - mu);
  for (int off = 1; off < 64; off <<= 1) sq += __shfl_xor(sq, off);
  float rs = rsqrtf(sq * (1.f / 512.f) + EPSC);

  float4 g0 = ((const float4*)gam)[lane], g1v = ((const float4*)gam)[lane + 64];
  float4 b0 = ((const float4*)bet)[lane], b1v = ((const float4*)bet)[lane + 64];
  float4 o0, o1;
  o0.x = (a0.x - mu) * rs * g0.x + b0.x;  o0.y = (a0.y - mu) * rs * g0.y + b0.y;
  o0.z = (a0.z - mu) * rs * g0.z + b0.z;  o0.w = (a0.w - mu) * rs * g0.w + b0.w;
  o1.x = (a1.x - mu) * rs * g1v.x + b1v.x; o1.y = (a1.y - mu) * rs * g1v.y + b1v.y;
  o1.z = (a1.z - mu) * rs * g1v.z + b1v.z; o1.w = (a1.w - mu) * rs * g1v.w + b1v.w;
  if (outf) {
    float* op = outf + (size_t)row * 512;
    ((float4*)op)[lane] = o0;
    ((float4*)op)[lane + 64] = o1;
  }
  if (outb) {
    bf16_t* op = outb + (size_t)row * 512;
    bf16x4 q0 = { (__bf16)o0.x, (__bf16)o0.y, (__bf16)o0.z, (__bf16)o0.w };
    bf16x4 q1 = { (__bf16)o1.x, (__bf16)o1.y, (__bf16)o1.z, (__bf16)o1.w };
    ((bf16x4*)op)[lane] = q0;
    ((bf16x4*)op)[lane + 64] = q1;
  }
}

// ---------------- v transpose: [B,N,H*64] -> vT [B,H,64,N] ----------------
__global__ __launch_bounds__(256) void k_vtrans(const bf16_t* __restrict__ v,
                                                bf16_t* __restrict__ vT) {
  int bid = blockIdx.x;
  int nt = bid & 15, h = (bid >> 4) & 7, b = bid >> 7;
  __shared__ bf16_t t[64 * 66];
  int tid = threadIdx.x, wid = tid >> 6, lane = tid & 63;
  for (int i = 0; i < 16; i++) {
    int n = wid * 16 + i;
    t[lane * 66 + n] = v[(size_t)(b * 1024 + nt * 64 + n) * 512 + h * 64 + lane];
  }
  __syncthreads();
  for (int i = 0; i < 16; i++) {
    int d = wid * 16 + i;
    vT[(size_t)((b * 8 + h) * 64 + d) * 1024 + nt * 64 + lane] = t[d * 66 + lane];
  }
}

// ---------------- max_n |k[b,h,n,:]| ----------------
__global__ __launch_bounds__(256) void k_knorm(const bf16_t* __restrict__ kk,
                                               float* __restrict__ kmax) {
  int bh = blockIdx.x;
  int b = bh >> 3, h = bh & 7;
  int tid = threadIdx.x;
  float mx = 0.f;
  for (int n = tid; n < 1024; n += 256) {
    const bf16_t* kp = kk + (size_t)(b * 1024 + n) * 512 + h * 64;
    float ss = 0.f;
#pragma unroll
    for (int vv = 0; vv < 8; vv++) {
      bf16x8 kv = *(const bf16x8*)(kp + vv * 8);
#pragma unroll
      for (int e = 0; e < 8; e++) { float f = (float)kv[e]; ss += f * f; }
    }
    mx = fmaxf(mx, ss);
  }
  for (int off = 1; off < 64; off <<= 1) mx = fmaxf(mx, __shfl_xor(mx, off));
  __shared__ float red[4];
  if ((tid & 63) == 0) red[tid >> 6] = mx;
  __syncthreads();
  if (tid == 0) kmax[bh] = sqrtf(fmaxf(fmaxf(red[0], red[1]), fmaxf(red[2], red[3])));
}

// ---------------- score upper bound C[b,h,n] = |q'| * kmax ----------------
__global__ __launch_bounds__(256) void k_cbound(const bf16_t* __restrict__ q,
                                                const float* __restrict__ kmax,
                                                float* __restrict__ Cb) {
  int t = blockIdx.x * 256 + threadIdx.x;  // (b*8+h)*1024 + n
  int b = t >> 13, h = (t >> 10) & 7;
  int n = t & 1023; (void)n;
  const bf16_t* qp = q + (size_t)(b * 1024 + (t & 1023)) * 512 + h * 64;
  float ss = 0.f;
#pragma unroll
  for (int vv = 0; vv < 8; vv++) {
    bf16x8 kv = *(const bf16x8*)(qp + vv * 8);
#pragma unroll
    for (int e = 0; e < 8; e++) { float f = (float)kv[e]; ss += f * f; }
  }
  Cb[t] = sqrtf(ss) * kmax[b * 8 + h];
}

// ---------------- attention: ctx (normalized) + crl = C + ln(l) ----------------
// grid 1024: bid = qt(4) | h(3) | b(3). Block: 64 q (4 waves x 16), full k=1024
// (16 tiles of 64). K/vT dbuf-staged via global_load_lds (XOR swizzle).
// p = eadj * exp(s - C); eadj bf16 loads pipelined one tile ahead (eaA/eaB).
__global__ __launch_bounds__(256) void k_attn_ctx(const bf16_t* __restrict__ q,
                                                  const bf16_t* __restrict__ kk,
                                                  const bf16_t* __restrict__ vT,
                                                  const bf16_t* __restrict__ eadj,
                                                  const float* __restrict__ Cb,
                                                  bf16_t* __restrict__ ctx,
                                                  float* __restrict__ crl) {
  __shared__ bf16_t ldsK[2][4096];
  __shared__ bf16_t ldsV[2][4096];
  __shared__ bf16_t pt[4][16 * 72];
  int bid = blockIdx.x;
  int qt = bid & 15, h = (bid >> 4) & 7, b = bid >> 7;
  int tid = threadIdx.x, wid = tid >> 6, lane = tid & 63;
  int l16 = lane & 15, g = lane >> 4;
  int qg0 = qt * 64 + wid * 16;
  int kvbase = (b * 8 + h) * 64;

  int d0 = wid * 2048 + lane * 16;
  int row0 = d0 >> 7, row1 = (d0 + 1024) >> 7;
  int cb0 = ((d0 >> 4) & 7) ^ (row0 & 7);
  int cb1 = ((d0 >> 4) & 7) ^ (row1 & 7);
  const bf16_t* ksrc = kk + (size_t)(b * 1024) * 512 + h * 64;
  const bf16_t* vsrc = vT + (size_t)kvbase * 1024;

  auto stage = [&](int buf, int kc0) {
    gload_lds16(ksrc + (size_t)(kc0 + row0) * 512 + cb0 * 8, &ldsK[buf][wid * 1024]);
    gload_lds16(ksrc + (size_t)(kc0 + row1) * 512 + cb1 * 8, &ldsK[buf][wid * 1024 + 512]);
    gload_lds16(vsrc + (size_t)row0 * 1024 + kc0 + cb0 * 8, &ldsV[buf][wid * 1024]);
    gload_lds16(vsrc + (size_t)row1 * 1024 + kc0 + cb1 * 8, &ldsV[buf][wid * 1024 + 512]);
  };

  const bf16_t* qp = q + (size_t)(b * 1024 + qg0 + l16) * 512 + h * 64 + 8 * g;
  bf16x8 aq0 = *(const bf16x8*)qp;
  bf16x8 aq1 = *(const bf16x8*)(qp + 32);

  float Cj[4];
#pragma unroll
  for (int j = 0; j < 4; j++) Cj[j] = Cb[(b * 8 + h) * 1024 + qg0 + g * 4 + j];

  f32x4 cacc[4];
#pragma unroll
  for (int d = 0; d < 4; d++) cacc[d] = (f32x4){0.f, 0.f, 0.f, 0.f};
  float ls[4] = {0.f, 0.f, 0.f, 0.f};
  bf16_t* myp = pt[wid];
  int rph = l16 & 7;
  const bf16_t* erow = eadj + (size_t)(qg0 + g * 4) * 1024 + l16;

  bf16_t eaA[4][4], eaB[4][4];
  // prologue: stage tile 0, load ea for tile 0
  stage(0, 0);
#pragma unroll
  for (int cg = 0; cg < 4; cg++)
#pragma unroll
    for (int j = 0; j < 4; j++) eaA[cg][j] = erow[(size_t)j * 1024 + cg * 16];
  __syncthreads();

  auto tile = [&](int kt, int buf, bf16_t (&eaC)[4][4], bf16_t (&eaN)[4][4]) {
    int kc0 = kt * 64;
    int ktn = (kt + 1 < 16) ? kt + 1 : 15;
    stage(buf ^ 1, ktn * 64);
    // prefetch eadj for next tile (consumed next iteration -> full-tile cover)
#pragma unroll
    for (int cg = 0; cg < 4; cg++)
#pragma unroll
      for (int j = 0; j < 4; j++)
        eaN[cg][j] = erow[(size_t)j * 1024 + ktn * 64 + cg * 16];

    const char* curK = (const char*)ldsK[buf];
    const char* curV = (const char*)ldsV[buf];

#pragma unroll
    for (int cg = 0; cg < 4; cg++) {
      const char* krow = curK + ((cg * 16 + l16) << 7);
      bf16x8 k0 = *(const bf16x8*)(krow + ((g ^ rph) << 4));
      bf16x8 k1 = *(const bf16x8*)(krow + (((g + 4) ^ rph) << 4));
      f32x4 s = (f32x4){0.f, 0.f, 0.f, 0.f};
      __builtin_amdgcn_s_setprio(1);
      s = mfma16(aq0, k0, s);
      s = mfma16(aq1, k1, s);
      __builtin_amdgcn_s_setprio(0);
#pragma unroll
      for (int j = 0; j < 4; j++) {
        float p = (float)eaC[cg][j] * __expf(s[j] - Cj[j]);
        ls[j] += p;
        myp[(g * 4 + j) * 72 + cg * 16 + l16] = (__bf16)p;
      }
    }
#pragma unroll
    for (int half = 0; half < 2; half++) {
      bf16x8 pa = *(const bf16x8*)(myp + l16 * 72 + half * 32 + 8 * g);
      __builtin_amdgcn_s_setprio(1);
#pragma unroll
      for (int dg = 0; dg < 4; dg++) {
        const char* vrow = curV + ((dg * 16 + l16) << 7);
        bf16x8 vv = *(const bf16x8*)(vrow + (((g + half * 4) ^ rph) << 4));
        cacc[dg] = mfma16(pa, vv, cacc[dg]);
      }
      __builtin_amdgcn_s_setprio(0);
    }
    __syncthreads();
  };

  for (int k2 = 0; k2 < 8; k2++) {
    tile(2 * k2,     0, eaA, eaB);
    tile(2 * k2 + 1, 1, eaB, eaA);
  }

  // row sums over the 16 lanes of each row-group
#pragma unroll
  for (int j = 0; j < 4; j++)
    for (int off = 1; off < 16; off <<= 1) ls[j] += __shfl_xor(ls[j], off);
  float rc[4];
#pragma unroll
  for (int j = 0; j < 4; j++) rc[j] = (ls[j] > 0.f) ? (1.f / ls[j]) : 0.f;

#pragma unroll
  for (int dg = 0; dg < 4; dg++)
#pragma unroll
    for (int j = 0; j < 4; j++) {
      int row = qg0 + g * 4 + j;
      ctx[(size_t)(b * 1024 + row) * 512 + h * 64 + dg * 16 + l16] =
          (__bf16)(cacc[dg][j] * rc[j]);
    }
  if (l16 == 0) {
#pragma unroll
    for (int j = 0; j < 4; j++) {
      int li = (b * 8 + h) * 1024 + qg0 + g * 4 + j;
      crl[li] = (ls[j] > 0.f) ? (Cj[j] + __logf(ls[j])) : 1.0e30f;
    }
  }
}

// ---------------- attention mean over heads -> mout (barrier-free) ----------------
// grid 1024: bid = kq(3) | qt(4) | b(3). Wave owns 16q x 128k x 8h; K streamed
// through wave-private 2x4KB LDS bufs (counted vmcnt, no __syncthreads).
// mean = eadj * (1/8) * sum_h exp(s_h - crl_h).
__global__ __launch_bounds__(256, 4) void k_attn_mean(const bf16_t* __restrict__ q,
                                                      const bf16_t* __restrict__ kk,
                                                      const bf16_t* __restrict__ eadj,
                                                      const float* __restrict__ crl,
                                                      float* __restrict__ mout) {
  __shared__ bf16_t lds[4][2][2048];   // [wave][buf][4KB]
  int bid = blockIdx.x;
  int kq = bid & 7, qt = (bid >> 3) & 15, b = bid >> 7;
  int tid = threadIdx.x, wid = tid >> 6, lane = tid & 63;
  int l16 = lane & 15, g = lane >> 4;
  int qg0 = qt * 64 + wid * 16;
  int kbase = kq * 128;
  int rl = lane >> 3;
  int cb = (lane & 7) ^ rl;
  const bf16_t* ksrc = kk + (size_t)(b * 1024 + kbase) * 512;

  auto stage = [&](int t) {
    int h = t >> 2, c = t & 3;
    char* dst = (char*)&lds[wid][t & 1][0];
    const bf16_t* sp = ksrc + (size_t)(c * 32 + rl) * 512 + h * 64 + cb * 8;
#pragma unroll
    for (int i = 0; i < 4; i++)
      gload_lds16(sp + (size_t)i * 8 * 512, dst + i * 1024);
  };

  f32x4 macc[8];
#pragma unroll
  for (int kg = 0; kg < 8; kg++) macc[kg] = (f32x4){0.f, 0.f, 0.f, 0.f};

  stage(0);

  for (int h = 0; h < 8; h++) {
    const bf16_t* qp = q + (size_t)(b * 1024 + qg0 + l16) * 512 + h * 64 + 8 * g;
    bf16x8 aq0 = *(const bf16x8*)qp;
    bf16x8 aq1 = *(const bf16x8*)(qp + 32);
    f32x4 CR = *(const f32x4*)(crl + (b * 8 + h) * 1024 + qg0 + g * 4);
#pragma unroll
    for (int c = 0; c < 4; c++) {
      int t = h * 4 + c;
      __builtin_amdgcn_sched_barrier(0);
      if (t < 31) {
        stage(t + 1);
        __builtin_amdgcn_sched_barrier(0);
        asm volatile("s_waitcnt vmcnt(4)" ::: "memory");
      } else {
        asm volatile("s_waitcnt vmcnt(0)" ::: "memory");
      }
      __builtin_amdgcn_sched_barrier(0);
      const char* cK = (const char*)&lds[wid][t & 1][0];
#pragma unroll
      for (int cg = 0; cg < 2; cg++) {
        const char* krow = cK + ((cg * 16 + l16) << 7);
        bf16x8 k0 = *(const bf16x8*)(krow + ((g ^ (l16 & 7)) << 4));
        bf16x8 k1 = *(const bf16x8*)(krow + (((g + 4) ^ (l16 & 7)) << 4));
        f32x4 s = (f32x4){0.f, 0.f, 0.f, 0.f};
        s = mfma16(aq0, k0, s);
        s = mfma16(aq1, k1, s);
        int kg = c * 2 + cg;
#pragma unroll
        for (int j = 0; j < 4; j++)
          macc[kg][j] += __expf(s[j] - CR[j]);
      }
    }
  }

  // epilogue: multiply by eadj/8 and store
#pragma unroll
  for (int kg = 0; kg < 8; kg++)
#pragma unroll
    for (int j = 0; j < 4; j++) {
      size_t off = (size_t)(qg0 + g * 4 + j) * 1024 + kbase + kg * 16 + l16;
      mout[(size_t)b * 1048576 + off] = macc[kg][j] * (float)eadj[off] * 0.125f;
    }
}

extern "C" void kernel_launch(void* const* d_in, const int* in_sizes, int n_in,
                              void* d_out, int out_size, void* d_ws, size_t ws_size,
                              hipStream_t stream) {
  (void)in_sizes; (void)n_in; (void)out_size; (void)ws_size;
  const float* x   = (const float*)d_in[0];
  const float* adj = (const float*)d_in[1];
  const int*   msk = (const int*)d_in[2];
  const float* Wq  = (const float*)d_in[3];
  const float* Wk  = (const float*)d_in[4];
  const float* Wv  = (const float*)d_in[5];
  const float* Wo  = (const float*)d_in[6];
  const float* W1  = (const float*)d_in[7];
  const float* b1  = (const float*)d_in[8];
  const float* W2  = (const float*)d_in[9];
  const float* b2  = (const float*)d_in[10];
  const float* g1  = (const float*)d_in[11];
  const float* be1 = (const float*)d_in[12];
  const float* g2  = (const float*)d_in[13];
  const float* be2 = (const float*)d_in[14];

  float* out  = (float*)d_out;
  float* mout = out + (size_t)8 * 1024 * 512;

  char* ws = (char*)d_ws;
  const size_t MB = 1024 * 1024;
  bf16_t* wqb = (bf16_t*)(ws);
  bf16_t* wkb = (bf16_t*)(ws + 512 * 1024);
  bf16_t* wvb = (bf16_t*)(ws + 1 * MB);
  bf16_t* wob = (bf16_t*)(ws + 3 * MB / 2);
  bf16_t* w1b = (bf16_t*)(ws + 2 * MB);
  bf16_t* w2b = (bf16_t*)(ws + 4 * MB);
  float*  Cb   = (float*)(ws + 6 * MB);              // 256 KB
  float*  crl  = (float*)(ws + 6 * MB + 256 * 1024); // 256 KB (C + ln l)
  float*  kmax = (float*)(ws + 6 * MB + 768 * 1024); // 256 B
  bf16_t* xb   = (bf16_t*)(ws + 8 * MB);   // 8-16: x bf16; then ctx; then zb
  bf16_t* ctx  = xb;
  bf16_t* zb   = xb;
  bf16_t* qb   = (bf16_t*)(ws + 16 * MB);  // 16-24
  bf16_t* kb   = (bf16_t*)(ws + 24 * MB);  // 24-32
  bf16_t* vb   = (bf16_t*)(ws + 32 * MB);  // 32-40 (dead after vtrans)
  bf16_t* vT   = (bf16_t*)(ws + 40 * MB);  // 40-48 (dead after attn_ctx)
  float*  gout1 = (float*)(ws + 16 * MB);  // 16-32 f32 (wo-gemm -> resln1)
  bf16_t* hb    = (bf16_t*)(ws + 16 * MB); // 16-48 bf16 (ffn1 -> ffn2)
  float*  gout2 = (float*)(ws + 48 * MB);  // 48-64 f32 (ffn2 -> resln2)
  bf16_t* eadj  = (bf16_t*)(ws + 72 * MB); // 72-74 bf16 exp(adj)*mask table

  // converts
  k_cvt<<<4096, 256, 0, stream>>>(x, xb, 1048576);
  k_cvtw<<<3072, 256, 0, stream>>>(Wq, Wk, Wv, Wo, W1, W2,
                                   wqb, wkb, wvb, wob, w1b, w2b);

  k_prep<<<256, 256, 0, stream>>>(adj, msk, eadj);

  // QKV: one GEMM, N=1536 (wq|wk|wv contiguous); q output pre-scaled by 0.125
  k_gemm<0><<<64 * 12, 256, 0, stream>>>(xb, wqb, 512, 12, nullptr, qb, nullptr, 512);
  k_vtrans<<<1024, 256, 0, stream>>>(vb, vT);
  k_knorm<<<64, 256, 0, stream>>>(kb, kmax);
  k_cbound<<<256, 256, 0, stream>>>(qb, kmax, Cb);

  // attention: ctx (normalized, full-k) + crl, then mean
  k_attn_ctx<<<1024, 256, 0, stream>>>(qb, kb, vT, eadj, Cb, ctx, crl);
  k_attn_mean<<<1024, 256, 0, stream>>>(qb, kb, eadj, crl, mout);

  // Wo proj -> gout1 ; residual(x f32) + LN1 -> zb (bf16)
  k_gemm<2><<<64 * 4, 256, 0, stream>>>(ctx, wob, 512, 4, nullptr, nullptr, gout1, 512);
  k_resln<<<2048, 256, 0, stream>>>(gout1, x, nullptr, g1, be1, nullptr, zb);
  // FFN1: relu(zb @ W1^T + b1) -> hb
  k_gemm<1><<<64 * 16, 256, 0, stream>>>(zb, w1b, 512, 16, b1, hb, nullptr, 2048);
  // FFN2 -> gout2 ; residual(zb bf16) + LN2 -> out
  k_gemm<2><<<64 * 4, 256, 0, stream>>>(hb, w2b, 2048, 4, b2, nullptr, gout2, 512);
  k_resln<<<2048, 256, 0, stream>>>(gout2, nullptr, zb, g2, be2, out, nullptr);
}

// Round 9
// 244.627 us; speedup vs baseline: 1.0076x; 1.0076x over previous
//
#include <hip/hip_runtime.h>
#include <math.h>
#include <stdint.h>

// GraphTransformerLayer on MI355X (gfx950).
// B=8, N=1024, D=512, H=8, Dh=64, F=2048.
// Round 9: attn_ctx -> 512-thread blocks (8 waves share staged K/V, LDS 49KB,
//          3 blocks/CU), XCD-aligned grid decode; exp2 domain (q pre-scaled by
//          0.125*log2e) removes one VALU mul per score in ctx+mean.

using bf16_t = __bf16;
typedef __attribute__((__ext_vector_type__(8))) __bf16 bf16x8;
typedef __attribute__((__ext_vector_type__(4))) __bf16 bf16x4;
typedef __attribute__((__ext_vector_type__(4))) float  f32x4;

#define DEVI __device__ __forceinline__

DEVI f32x4 mfma16(bf16x8 a, bf16x8 b, f32x4 c) {
  return __builtin_amdgcn_mfma_f32_16x16x32_bf16(a, b, c, 0, 0, 0);
}

// async global->LDS, 16B per lane. dest = wave-uniform base (+ lane*16 by HW).
DEVI void gload_lds16(const void* g, void* l) {
  __builtin_amdgcn_global_load_lds(
      (const __attribute__((address_space(1))) uint32_t*)g,
      (__attribute__((address_space(3))) uint32_t*)l, 16, 0, 0);
}

#define EPSC  (1e-5f)
#define QSCALE 0.18033688f   // 0.125 * log2(e): scores come out of MFMA in base-2

// ---------------- f32 -> bf16 convert (vector4) ----------------
__global__ __launch_bounds__(256) void k_cvt(const float* __restrict__ in,
                                             bf16_t* __restrict__ out, int n4) {
  int i = blockIdx.x * 256 + threadIdx.x;
  if (i < n4) {
    float4 v = ((const float4*)in)[i];
    bf16x4 o = { (__bf16)v.x, (__bf16)v.y, (__bf16)v.z, (__bf16)v.w };
    ((bf16x4*)out)[i] = o;
  }
}

// ---------------- fused weight converts ----------------
__global__ __launch_bounds__(256) void k_cvtw(const float* __restrict__ wq,
                                              const float* __restrict__ wk,
                                              const float* __restrict__ wv,
                                              const float* __restrict__ wo,
                                              const float* __restrict__ w1,
                                              const float* __restrict__ w2,
                                              bf16_t* __restrict__ owq,
                                              bf16_t* __restrict__ owk,
                                              bf16_t* __restrict__ owv,
                                              bf16_t* __restrict__ owo,
                                              bf16_t* __restrict__ ow1,
                                              bf16_t* __restrict__ ow2) {
  int blk = blockIdx.x;
  const float* src; bf16_t* dst; int base;
  if      (blk < 256)  { src = wq; dst = owq; base = blk; }
  else if (blk < 512)  { src = wk; dst = owk; base = blk - 256; }
  else if (blk < 768)  { src = wv; dst = owv; base = blk - 512; }
  else if (blk < 1024) { src = wo; dst = owo; base = blk - 768; }
  else if (blk < 2048) { src = w1; dst = ow1; base = blk - 1024; }
  else                 { src = w2; dst = ow2; base = blk - 2048; }
  int i = base * 256 + threadIdx.x;
  float4 v = ((const float4*)src)[i];
  bf16x4 o = { (__bf16)v.x, (__bf16)v.y, (__bf16)v.z, (__bf16)v.w };
  ((bf16x4*)dst)[i] = o;
}

// ---------------- eadj = mask ? exp(adj) : 0  (bf16 table) ----------------
__global__ __launch_bounds__(256) void k_prep(const float* __restrict__ adj,
                                              const int* __restrict__ msk,
                                              bf16_t* __restrict__ eadj) {
  int row  = blockIdx.x * 4 + (threadIdx.x >> 6);
  int lane = threadIdx.x & 63;
  for (int i = 0; i < 16; i++) {
    int c = lane + 64 * i;
    size_t idx = (size_t)row * 1024 + c;
    float a = adj[idx];
    bool valid = (msk[idx] != 0);
    eadj[idx] = valid ? (__bf16)__expf(a) : (__bf16)0.f;
  }
}

// ---------------- tiled GEMM: C[8192 x N] = A[8192 x K] @ B[N x K]^T ----------------
// 128x128 tile, 4 waves (2x2), each wave 64x64 (4x4 fragments). BK=32.
template<int EPI>
__global__ __launch_bounds__(256) void k_gemm(const bf16_t* __restrict__ A,
                                              const bf16_t* __restrict__ B,
                                              int K, int nbx,
                                              const float* __restrict__ bias,
                                              bf16_t* __restrict__ outb,
                                              float* __restrict__ outf,
                                              int out_ncols) {
  __shared__ bf16_t lA[2][4096];
  __shared__ bf16_t lB[2][4096];
  int bid = blockIdx.x;
  int nb = bid % nbx, mb = bid / nbx;
  int tid = threadIdx.x, wid = tid >> 6, lane = tid & 63;
  int l16 = lane & 15, g = lane >> 4;
  int wr = wid >> 1, wc = wid & 1;
  int rowbase = mb * 128, c0 = nb * 128;

  int dA0 = wid * 2048 + lane * 16;
  int rA0 = dA0 >> 6;
  int cbA = ((dA0 >> 4) & 3) ^ (rA0 & 3);
  const bf16_t* Asrc0 = A + (size_t)(rowbase + rA0) * K + cbA * 8;
  const bf16_t* Asrc1 = A + (size_t)(rowbase + rA0 + 16) * K + cbA * 8;
  const bf16_t* Bsrc0 = B + (size_t)(c0 + rA0) * K + cbA * 8;
  const bf16_t* Bsrc1 = B + (size_t)(c0 + rA0 + 16) * K + cbA * 8;

  f32x4 acc[4][4];
#pragma unroll
  for (int m = 0; m < 4; m++)
#pragma unroll
    for (int n = 0; n < 4; n++) acc[m][n] = (f32x4){0.f, 0.f, 0.f, 0.f};

  gload_lds16(Asrc0, (char*)&lA[0][0] + wid * 2048);
  gload_lds16(Asrc1, (char*)&lA[0][0] + wid * 2048 + 1024);
  gload_lds16(Bsrc0, (char*)&lB[0][0] + wid * 2048);
  gload_lds16(Bsrc1, (char*)&lB[0][0] + wid * 2048 + 1024);
  __syncthreads();

  for (int k0 = 0; k0 < K; k0 += 32) {
    int buf = (k0 >> 5) & 1;
    if (k0 + 32 < K) {
      gload_lds16(Asrc0 + k0 + 32, (char*)&lA[buf ^ 1][0] + wid * 2048);
      gload_lds16(Asrc1 + k0 + 32, (char*)&lA[buf ^ 1][0] + wid * 2048 + 1024);
      gload_lds16(Bsrc0 + k0 + 32, (char*)&lB[buf ^ 1][0] + wid * 2048);
      gload_lds16(Bsrc1 + k0 + 32, (char*)&lB[buf ^ 1][0] + wid * 2048 + 1024);
    }
    const char* cA = (const char*)&lA[buf][0];
    const char* cB = (const char*)&lB[buf][0];
    bf16x8 af[4], bq[4];
#pragma unroll
    for (int m = 0; m < 4; m++) {
      int row = wr * 64 + m * 16 + l16;
      af[m] = *(const bf16x8*)(cA + row * 64 + ((g ^ (row & 3)) << 4));
    }
#pragma unroll
    for (int n = 0; n < 4; n++) {
      int row = wc * 64 + n * 16 + l16;
      bq[n] = *(const bf16x8*)(cB + row * 64 + ((g ^ (row & 3)) << 4));
    }
#pragma unroll
    for (int m = 0; m < 4; m++)
#pragma unroll
      for (int n = 0; n < 4; n++) acc[m][n] = mfma16(af[m], bq[n], acc[m][n]);
    __syncthreads();
  }

  int which = c0 / out_ncols;
  int cloc0 = c0 - which * out_ncols;
  size_t obase = (size_t)which * 8192 * out_ncols;
  float osc = (EPI == 0 && which == 0) ? QSCALE : 1.0f;  // q pre-scale (base-2)
#pragma unroll
  for (int n = 0; n < 4; n++) {
    int col = cloc0 + wc * 64 + n * 16 + l16;
    float bv = (EPI >= 1 && bias) ? bias[col] : 0.f;
#pragma unroll
    for (int m = 0; m < 4; m++)
#pragma unroll
      for (int j = 0; j < 4; j++) {
        int row = rowbase + wr * 64 + m * 16 + g * 4 + j;
        float v = acc[m][n][j] + bv;
        size_t idx = obase + (size_t)row * out_ncols + col;
        if (EPI == 1) outb[idx] = (__bf16)fmaxf(v, 0.f);
        else if (EPI == 0) outb[idx] = (__bf16)(v * osc);
        else outf[idx] = v;
      }
  }
}

// ---------------- residual + LayerNorm (memory-bound): rows of 512 ----------------
__global__ __launch_bounds__(256) void k_resln(const float* __restrict__ gin,
                                               const float* __restrict__ residf,
                                               const bf16_t* __restrict__ residb,
                                               const float* __restrict__ gam,
                                               const float* __restrict__ bet,
                                               float* __restrict__ outf,
                                               bf16_t* __restrict__ outb) {
  int row = blockIdx.x * 4 + (threadIdx.x >> 6);
  int lane = threadIdx.x & 63;
  const float* gp = gin + (size_t)row * 512;
  float4 a0 = ((const float4*)gp)[lane];
  float4 a1 = ((const float4*)gp)[lane + 64];
  if (residf) {
    const float* rp = residf + (size_t)row * 512;
    float4 r0 = ((const float4*)rp)[lane];
    float4 r1 = ((const float4*)rp)[lane + 64];
    a0.x += r0.x; a0.y += r0.y; a0.z += r0.z; a0.w += r0.w;
    a1.x += r1.x; a1.y += r1.y; a1.z += r1.z; a1.w += r1.w;
  } else {
    const bf16_t* rp = residb + (size_t)row * 512;
    bf16x4 r0 = ((const bf16x4*)rp)[lane];
    bf16x4 r1 = ((const bf16x4*)rp)[lane + 64];
    a0.x += (float)r0[0]; a0.y += (float)r0[1]; a0.z += (float)r0[2]; a0.w += (float)r0[3];
    a1.x += (float)r1[0]; a1.y += (float)r1[1]; a1.z += (float)r1[2]; a1.w += (float)r1[3];
  }
  float s = a0.x + a0.y + a0.z + a0.w + a1.x + a1.y + a1.z + a1.w;
  for (int off = 1; off < 64; off <<= 1) s += __shfl_xor(s, off);
  float mu = s * (1.f / 512.f);
  float sq = (a0.x - mu) * (a0.x - mu) + (a0.y - mu) * (a0.y - mu) +
             (a0.z - mu) * (a0.z - mu) + (a0.w - mu) * (a0.w - mu) +
             (a1.x - mu) * (a1.x - mu) + (a1.y - mu) * (a1.y - mu) +
             (a1.z - mu) * (a1.z - mu) + (a1.w - mu) * (a1.w - mu);
  for (int off = 1; off < 64; off <<= 1) sq += __shfl_xor(sq, off);
  float rs = rsqrtf(sq * (1.f / 512.f) + EPSC);

  float4 g0 = ((const float4*)gam)[lane], g1v = ((const float4*)gam)[lane + 64];
  float4 b0 = ((const float4*)bet)[lane], b1v = ((const float4*)bet)[lane + 64];
  float4 o0, o1;
  o0.x = (a0.x - mu) * rs * g0.x + b0.x;  o0.y = (a0.y - mu) * rs * g0.y + b0.y;
  o0.z = (a0.z - mu) * rs * g0.z + b0.z;  o0.w = (a0.w - mu) * rs * g0.w + b0.w;
  o1.x = (a1.x - mu) * rs * g1v.x + b1v.x; o1.y = (a1.y - mu) * rs * g1v.y + b1v.y;
  o1.z = (a1.z - mu) * rs * g1v.z + b1v.z; o1.w = (a1.w - mu) * rs * g1v.w + b1v.w;
  if (outf) {
    float* op = outf + (size_t)row * 512;
    ((float4*)op)[lane] = o0;
    ((float4*)op)[lane + 64] = o1;
  }
  if (outb) {
    bf16_t* op = outb + (size_t)row * 512;
    bf16x4 q0 = { (__bf16)o0.x, (__bf16)o0.y, (__bf16)o0.z, (__bf16)o0.w };
    bf16x4 q1 = { (__bf16)o1.x, (__bf16)o1.y, (__bf16)o1.z, (__bf16)o1.w };
    ((bf16x4*)op)[lane] = q0;
    ((bf16x4*)op)[lane + 64] = q1;
  }
}

// ---------------- v transpose: [B,N,H*64] -> vT [B,H,64,N] ----------------
__global__ __launch_bounds__(256) void k_vtrans(const bf16_t* __restrict__ v,
                                                bf16_t* __restrict__ vT) {
  int bid = blockIdx.x;
  int nt = bid & 15, h = (bid >> 4) & 7, b = bid >> 7;
  __shared__ bf16_t t[64 * 66];
  int tid = threadIdx.x, wid = tid >> 6, lane = tid & 63;
  for (int i = 0; i < 16; i++) {
    int n = wid * 16 + i;
    t[lane * 66 + n] = v[(size_t)(b * 1024 + nt * 64 + n) * 512 + h * 64 + lane];
  }
  __syncthreads();
  for (int i = 0; i < 16; i++) {
    int d = wid * 16 + i;
    vT[(size_t)((b * 8 + h) * 64 + d) * 1024 + nt * 64 + lane] = t[d * 66 + lane];
  }
}

// ---------------- max_n |k[b,h,n,:]| ----------------
__global__ __launch_bounds__(256) void k_knorm(const bf16_t* __restrict__ kk,
                                               float* __restrict__ kmax) {
  int bh = blockIdx.x;
  int b = bh >> 3, h = bh & 7;
  int tid = threadIdx.x;
  float mx = 0.f;
  for (int n = tid; n < 1024; n += 256) {
    const bf16_t* kp = kk + (size_t)(b * 1024 + n) * 512 + h * 64;
    float ss = 0.f;
#pragma unroll
    for (int vv = 0; vv < 8; vv++) {
      bf16x8 kv = *(const bf16x8*)(kp + vv * 8);
#pragma unroll
      for (int e = 0; e < 8; e++) { float f = (float)kv[e]; ss += f * f; }
    }
    mx = fmaxf(mx, ss);
  }
  for (int off = 1; off < 64; off <<= 1) mx = fmaxf(mx, __shfl_xor(mx, off));
  __shared__ float red[4];
  if ((tid & 63) == 0) red[tid >> 6] = mx;
  __syncthreads();
  if (tid == 0) kmax[bh] = sqrtf(fmaxf(fmaxf(red[0], red[1]), fmaxf(red[2], red[3])));
}

// ---------------- score upper bound C[b,h,n] = |q'| * kmax (base-2 domain) ----------------
__global__ __launch_bounds__(256) void k_cbound(const bf16_t* __restrict__ q,
                                                const float* __restrict__ kmax,
                                                float* __restrict__ Cb) {
  int t = blockIdx.x * 256 + threadIdx.x;  // (b*8+h)*1024 + n
  int b = t >> 13, h = (t >> 10) & 7;
  const bf16_t* qp = q + (size_t)(b * 1024 + (t & 1023)) * 512 + h * 64;
  float ss = 0.f;
#pragma unroll
  for (int vv = 0; vv < 8; vv++) {
    bf16x8 kv = *(const bf16x8*)(qp + vv * 8);
#pragma unroll
    for (int e = 0; e < 8; e++) { float f = (float)kv[e]; ss += f * f; }
  }
  Cb[t] = sqrtf(ss) * kmax[b * 8 + h];
}

// ---------------- attention: ctx (normalized) + crl = C + log2(l) ----------------
// grid 512: bid = qt*64 + (h + 8b)  [same-(h,b) panel blocks share an XCD].
// Block: 512 threads (8 waves x 16 q-rows = 128 q), full k = 16 tiles of 64.
// K/vT dbuf-staged via global_load_lds (XOR swizzle), shared by 8 waves.
// p = eadj * exp2(s - C)  (q pre-scaled by 0.125*log2e).
__global__ __launch_bounds__(512) void k_attn_ctx(const bf16_t* __restrict__ q,
                                                  const bf16_t* __restrict__ kk,
                                                  const bf16_t* __restrict__ vT,
                                                  const bf16_t* __restrict__ eadj,
                                                  const float* __restrict__ Cb,
                                                  bf16_t* __restrict__ ctx,
                                                  float* __restrict__ crl) {
  __shared__ bf16_t ldsK[2][4096];
  __shared__ bf16_t ldsV[2][4096];
  __shared__ bf16_t pt[8][16 * 68];
  int bid = blockIdx.x;
  int qt = bid >> 6, h = bid & 7, b = (bid >> 3) & 7;
  int tid = threadIdx.x, wid = tid >> 6, lane = tid & 63;
  int l16 = lane & 15, g = lane >> 4;
  int qg0 = qt * 128 + wid * 16;
  int kvbase = (b * 8 + h) * 64;

  // staging: wave wid stages bytes [wid*1024, +1024) of each 8KB tile (1 instr each)
  int d0 = wid * 1024 + lane * 16;
  int row0 = d0 >> 7;
  int cb0 = ((d0 >> 4) & 7) ^ (row0 & 7);
  const bf16_t* ksrc = kk + (size_t)(b * 1024) * 512 + h * 64;
  const bf16_t* vsrc = vT + (size_t)kvbase * 1024;

  auto stage = [&](int buf, int kc0) {
    gload_lds16(ksrc + (size_t)(kc0 + row0) * 512 + cb0 * 8, &ldsK[buf][wid * 512]);
    gload_lds16(vsrc + (size_t)row0 * 1024 + kc0 + cb0 * 8, &ldsV[buf][wid * 512]);
  };

  const bf16_t* qp = q + (size_t)(b * 1024 + qg0 + l16) * 512 + h * 64 + 8 * g;
  bf16x8 aq0 = *(const bf16x8*)qp;
  bf16x8 aq1 = *(const bf16x8*)(qp + 32);

  float Cj[4];
#pragma unroll
  for (int j = 0; j < 4; j++) Cj[j] = Cb[(b * 8 + h) * 1024 + qg0 + g * 4 + j];

  f32x4 cacc[4];
#pragma unroll
  for (int d = 0; d < 4; d++) cacc[d] = (f32x4){0.f, 0.f, 0.f, 0.f};
  float ls[4] = {0.f, 0.f, 0.f, 0.f};
  bf16_t* myp = pt[wid];
  int rph = l16 & 7;
  const bf16_t* erow = eadj + (size_t)(qg0 + g * 4) * 1024 + l16;

  bf16_t eaA[4][4], eaB[4][4];
  stage(0, 0);
#pragma unroll
  for (int cg = 0; cg < 4; cg++)
#pragma unroll
    for (int j = 0; j < 4; j++) eaA[cg][j] = erow[(size_t)j * 1024 + cg * 16];
  __syncthreads();

  auto tile = [&](int kt, int buf, bf16_t (&eaC)[4][4], bf16_t (&eaN)[4][4]) {
    int kc0 = kt * 64;
    int ktn = (kt + 1 < 16) ? kt + 1 : 15;
    stage(buf ^ 1, ktn * 64);
#pragma unroll
    for (int cg = 0; cg < 4; cg++)
#pragma unroll
      for (int j = 0; j < 4; j++)
        eaN[cg][j] = erow[(size_t)j * 1024 + ktn * 64 + cg * 16];

    const char* curK = (const char*)ldsK[buf];
    const char* curV = (const char*)ldsV[buf];

#pragma unroll
    for (int cg = 0; cg < 4; cg++) {
      const char* krow = curK + ((cg * 16 + l16) << 7);
      bf16x8 k0 = *(const bf16x8*)(krow + ((g ^ rph) << 4));
      bf16x8 k1 = *(const bf16x8*)(krow + (((g + 4) ^ rph) << 4));
      f32x4 s = (f32x4){0.f, 0.f, 0.f, 0.f};
      __builtin_amdgcn_s_setprio(1);
      s = mfma16(aq0, k0, s);
      s = mfma16(aq1, k1, s);
      __builtin_amdgcn_s_setprio(0);
#pragma unroll
      for (int j = 0; j < 4; j++) {
        float p = (float)eaC[cg][j] * exp2f(s[j] - Cj[j]);
        ls[j] += p;
        myp[(g * 4 + j) * 68 + cg * 16 + l16] = (__bf16)p;
      }
    }
#pragma unroll
    for (int half = 0; half < 2; half++) {
      bf16x8 pa = *(const bf16x8*)(myp + l16 * 68 + half * 32 + 8 * g);
      __builtin_amdgcn_s_setprio(1);
#pragma unroll
      for (int dg = 0; dg < 4; dg++) {
        const char* vrow = curV + ((dg * 16 + l16) << 7);
        bf16x8 vv = *(const bf16x8*)(vrow + (((g + half * 4) ^ rph) << 4));
        cacc[dg] = mfma16(pa, vv, cacc[dg]);
      }
      __builtin_amdgcn_s_setprio(0);
    }
    __syncthreads();
  };

  for (int k2 = 0; k2 < 8; k2++) {
    tile(2 * k2,     0, eaA, eaB);
    tile(2 * k2 + 1, 1, eaB, eaA);
  }

#pragma unroll
  for (int j = 0; j < 4; j++)
    for (int off = 1; off < 16; off <<= 1) ls[j] += __shfl_xor(ls[j], off);
  float rc[4];
#pragma unroll
  for (int j = 0; j < 4; j++) rc[j] = (ls[j] > 0.f) ? (1.f / ls[j]) : 0.f;

#pragma unroll
  for (int dg = 0; dg < 4; dg++)
#pragma unroll
    for (int j = 0; j < 4; j++) {
      int row = qg0 + g * 4 + j;
      ctx[(size_t)(b * 1024 + row) * 512 + h * 64 + dg * 16 + l16] =
          (__bf16)(cacc[dg][j] * rc[j]);
    }
  if (l16 == 0) {
#pragma unroll
    for (int j = 0; j < 4; j++) {
      int li = (b * 8 + h) * 1024 + qg0 + g * 4 + j;
      crl[li] = (ls[j] > 0.f) ? (Cj[j] + __log2f(ls[j])) : 1.0e30f;
    }
  }
}

// ---------------- attention mean over heads -> mout (barrier-free) ----------------
// mean = eadj * (1/8) * sum_h exp2(s_h - crl_h)   (base-2 domain).
__global__ __launch_bounds__(256, 4) void k_attn_mean(const bf16_t* __restrict__ q,
                                                      const bf16_t* __restrict__ kk,
                                                      const bf16_t* __restrict__ eadj,
                                                      const float* __restrict__ crl,
                                                      float* __restrict__ mout) {
  __shared__ bf16_t lds[4][2][2048];   // [wave][buf][4KB]
  int bid = blockIdx.x;
  int kq = bid & 7, qt = (bid >> 3) & 15, b = bid >> 7;
  int tid = threadIdx.x, wid = tid >> 6, lane = tid & 63;
  int l16 = lane & 15, g = lane >> 4;
  int qg0 = qt * 64 + wid * 16;
  int kbase = kq * 128;
  int rl = lane >> 3;
  int cb = (lane & 7) ^ rl;
  const bf16_t* ksrc = kk + (size_t)(b * 1024 + kbase) * 512;

  auto stage = [&](int t) {
    int h = t >> 2, c = t & 3;
    char* dst = (char*)&lds[wid][t & 1][0];
    const bf16_t* sp = ksrc + (size_t)(c * 32 + rl) * 512 + h * 64 + cb * 8;
#pragma unroll
    for (int i = 0; i < 4; i++)
      gload_lds16(sp + (size_t)i * 8 * 512, dst + i * 1024);
  };

  f32x4 macc[8];
#pragma unroll
  for (int kg = 0; kg < 8; kg++) macc[kg] = (f32x4){0.f, 0.f, 0.f, 0.f};

  stage(0);

  for (int h = 0; h < 8; h++) {
    const bf16_t* qp = q + (size_t)(b * 1024 + qg0 + l16) * 512 + h * 64 + 8 * g;
    bf16x8 aq0 = *(const bf16x8*)qp;
    bf16x8 aq1 = *(const bf16x8*)(qp + 32);
    f32x4 CR = *(const f32x4*)(crl + (b * 8 + h) * 1024 + qg0 + g * 4);
#pragma unroll
    for (int c = 0; c < 4; c++) {
      int t = h * 4 + c;
      __builtin_amdgcn_sched_barrier(0);
      if (t < 31) {
        stage(t + 1);
        __builtin_amdgcn_sched_barrier(0);
        asm volatile("s_waitcnt vmcnt(4)" ::: "memory");
      } else {
        asm volatile("s_waitcnt vmcnt(0)" ::: "memory");
      }
      __builtin_amdgcn_sched_barrier(0);
      const char* cK = (const char*)&lds[wid][t & 1][0];
#pragma unroll
      for (int cg = 0; cg < 2; cg++) {
        const char* krow = cK + ((cg * 16 + l16) << 7);
        bf16x8 k0 = *(const bf16x8*)(krow + ((g ^ (l16 & 7)) << 4));
        bf16x8 k1 = *(const bf16x8*)(krow + (((g + 4) ^ (l16 & 7)) << 4));
        f32x4 s = (f32x4){0.f, 0.f, 0.f, 0.f};
        __builtin_amdgcn_s_setprio(1);
        s = mfma16(aq0, k0, s);
        s = mfma16(aq1, k1, s);
        __builtin_amdgcn_s_setprio(0);
        int kg = c * 2 + cg;
#pragma unroll
        for (int j = 0; j < 4; j++)
          macc[kg][j] += exp2f(s[j] - CR[j]);
      }
    }
  }

#pragma unroll
  for (int kg = 0; kg < 8; kg++)
#pragma unroll
    for (int j = 0; j < 4; j++) {
      size_t off = (size_t)(qg0 + g * 4 + j) * 1024 + kbase + kg * 16 + l16;
      mout[(size_t)b * 1048576 + off] = macc[kg][j] * (float)eadj[off] * 0.125f;
    }
}

extern "C" void kernel_launch(void* const* d_in, const int* in_sizes, int n_in,
                              void* d_out, int out_size, void* d_ws, size_t ws_size,
                              hipStream_t stream) {
  (void)in_sizes; (void)n_in; (void)out_size; (void)ws_size;
  const float* x   = (const float*)d_in[0];
  const float* adj = (const float*)d_in[1];
  const int*   msk = (const int*)d_in[2];
  const float* Wq  = (const float*)d_in[3];
  const float* Wk  = (const float*)d_in[4];
  const float* Wv  = (const float*)d_in[5];
  const float* Wo  = (const float*)d_in[6];
  const float* W1  = (const float*)d_in[7];
  const float* b1  = (const float*)d_in[8];
  const float* W2  = (const float*)d_in[9];
  const float* b2  = (const float*)d_in[10];
  const float* g1  = (const float*)d_in[11];
  const float* be1 = (const float*)d_in[12];
  const float* g2  = (const float*)d_in[13];
  const float* be2 = (const float*)d_in[14];

  float* out  = (float*)d_out;
  float* mout = out + (size_t)8 * 1024 * 512;

  char* ws = (char*)d_ws;
  const size_t MB = 1024 * 1024;
  bf16_t* wqb = (bf16_t*)(ws);
  bf16_t* wkb = (bf16_t*)(ws + 512 * 1024);
  bf16_t* wvb = (bf16_t*)(ws + 1 * MB);
  bf16_t* wob = (bf16_t*)(ws + 3 * MB / 2);
  bf16_t* w1b = (bf16_t*)(ws + 2 * MB);
  bf16_t* w2b = (bf16_t*)(ws + 4 * MB);
  float*  Cb   = (float*)(ws + 6 * MB);              // 256 KB
  float*  crl  = (float*)(ws + 6 * MB + 256 * 1024); // 256 KB (C + log2 l)
  float*  kmax = (float*)(ws + 6 * MB + 768 * 1024); // 256 B
  bf16_t* xb   = (bf16_t*)(ws + 8 * MB);   // 8-16: x bf16; then ctx; then zb
  bf16_t* ctx  = xb;
  bf16_t* zb   = xb;
  bf16_t* qb   = (bf16_t*)(ws + 16 * MB);  // 16-24
  bf16_t* kb   = (bf16_t*)(ws + 24 * MB);  // 24-32
  bf16_t* vb   = (bf16_t*)(ws + 32 * MB);  // 32-40 (dead after vtrans)
  bf16_t* vT   = (bf16_t*)(ws + 40 * MB);  // 40-48 (dead after attn_ctx)
  float*  gout1 = (float*)(ws + 16 * MB);  // 16-32 f32 (wo-gemm -> resln1)
  bf16_t* hb    = (bf16_t*)(ws + 16 * MB); // 16-48 bf16 (ffn1 -> ffn2)
  float*  gout2 = (float*)(ws + 48 * MB);  // 48-64 f32 (ffn2 -> resln2)
  bf16_t* eadj  = (bf16_t*)(ws + 72 * MB); // 72-74 bf16 exp(adj)*mask table

  // converts
  k_cvt<<<4096, 256, 0, stream>>>(x, xb, 1048576);
  k_cvtw<<<3072, 256, 0, stream>>>(Wq, Wk, Wv, Wo, W1, W2,
                                   wqb, wkb, wvb, wob, w1b, w2b);

  k_prep<<<256, 256, 0, stream>>>(adj, msk, eadj);

  // QKV: one GEMM, N=1536 (wq|wk|wv contiguous); q pre-scaled by 0.125*log2e
  k_gemm<0><<<64 * 12, 256, 0, stream>>>(xb, wqb, 512, 12, nullptr, qb, nullptr, 512);
  k_vtrans<<<1024, 256, 0, stream>>>(vb, vT);
  k_knorm<<<64, 256, 0, stream>>>(kb, kmax);
  k_cbound<<<256, 256, 0, stream>>>(qb, kmax, Cb);

  // attention: ctx (normalized, full-k, 512-thr blocks) + crl, then mean
  k_attn_ctx<<<512, 512, 0, stream>>>(qb, kb, vT, eadj, Cb, ctx, crl);
  k_attn_mean<<<1024, 256, 0, stream>>>(qb, kb, eadj, crl, mout);

  // Wo proj -> gout1 ; residual(x f32) + LN1 -> zb (bf16)
  k_gemm<2><<<64 * 4, 256, 0, stream>>>(ctx, wob, 512, 4, nullptr, nullptr, gout1, 512);
  k_resln<<<2048, 256, 0, stream>>>(gout1, x, nullptr, g1, be1, nullptr, zb);
  // FFN1: relu(zb @ W1^T + b1) -> hb
  k_gemm<1><<<64 * 16, 256, 0, stream>>>(zb, w1b, 512, 16, b1, hb, nullptr, 2048);
  // FFN2 -> gout2 ; residual(zb bf16) + LN2 -> out
  k_gemm<2><<<64 * 4, 256, 0, stream>>>(hb, w2b, 2048, 4, b2, nullptr, gout2, 512);
  k_resln<<<2048, 256, 0, stream>>>(gout2, nullptr, zb, g2, be2, out, nullptr);
}

// Round 10
// 231.265 us; speedup vs baseline: 1.0658x; 1.0578x over previous
//
#include <hip/hip_runtime.h>
#include <math.h>
#include <stdint.h>

// GraphTransformerLayer on MI355X (gfx950).
// B=8, N=1024, D=512, H=8, Dh=64, F=2048.
// Round 10: split-K x2 for FFN2/Wo gemms (partials summed in resln);
//           cbound folded into attn_ctx (in-register |q|*kmax);
//           cvt+cvtw and vtrans+knorm launch merges (14 -> 11 launches).

using bf16_t = __bf16;
typedef __attribute__((__ext_vector_type__(8))) __bf16 bf16x8;
typedef __attribute__((__ext_vector_type__(4))) __bf16 bf16x4;
typedef __attribute__((__ext_vector_type__(4))) float  f32x4;

#define DEVI __device__ __forceinline__

DEVI f32x4 mfma16(bf16x8 a, bf16x8 b, f32x4 c) {
  return __builtin_amdgcn_mfma_f32_16x16x32_bf16(a, b, c, 0, 0, 0);
}

// async global->LDS, 16B per lane. dest = wave-uniform base (+ lane*16 by HW).
DEVI void gload_lds16(const void* g, void* l) {
  __builtin_amdgcn_global_load_lds(
      (const __attribute__((address_space(1))) uint32_t*)g,
      (__attribute__((address_space(3))) uint32_t*)l, 16, 0, 0);
}

#define EPSC  (1e-5f)
#define QSCALE 0.18033688f   // 0.125 * log2(e): scores come out of MFMA in base-2

// ---------------- fused f32->bf16 converts: x (4096 blks) + weights (3072) ----------------
__global__ __launch_bounds__(256) void k_cvtall(const float* __restrict__ x,
                                                const float* __restrict__ wq,
                                                const float* __restrict__ wk,
                                                const float* __restrict__ wv,
                                                const float* __restrict__ wo,
                                                const float* __restrict__ w1,
                                                const float* __restrict__ w2,
                                                bf16_t* __restrict__ ox,
                                                bf16_t* __restrict__ owq,
                                                bf16_t* __restrict__ owk,
                                                bf16_t* __restrict__ owv,
                                                bf16_t* __restrict__ owo,
                                                bf16_t* __restrict__ ow1,
                                                bf16_t* __restrict__ ow2) {
  int blk = blockIdx.x;
  const float* src; bf16_t* dst; int base;
  if (blk < 4096)      { src = x;  dst = ox;  base = blk; }
  else {
    blk -= 4096;
    if      (blk < 256)  { src = wq; dst = owq; base = blk; }
    else if (blk < 512)  { src = wk; dst = owk; base = blk - 256; }
    else if (blk < 768)  { src = wv; dst = owv; base = blk - 512; }
    else if (blk < 1024) { src = wo; dst = owo; base = blk - 768; }
    else if (blk < 2048) { src = w1; dst = ow1; base = blk - 1024; }
    else                 { src = w2; dst = ow2; base = blk - 2048; }
  }
  int i = base * 256 + threadIdx.x;
  float4 v = ((const float4*)src)[i];
  bf16x4 o = { (__bf16)v.x, (__bf16)v.y, (__bf16)v.z, (__bf16)v.w };
  ((bf16x4*)dst)[i] = o;
}

// ---------------- eadj = mask ? exp(adj) : 0  (bf16 table) ----------------
__global__ __launch_bounds__(256) void k_prep(const float* __restrict__ adj,
                                              const int* __restrict__ msk,
                                              bf16_t* __restrict__ eadj) {
  int row  = blockIdx.x * 4 + (threadIdx.x >> 6);
  int lane = threadIdx.x & 63;
  for (int i = 0; i < 16; i++) {
    int c = lane + 64 * i;
    size_t idx = (size_t)row * 1024 + c;
    float a = adj[idx];
    bool valid = (msk[idx] != 0);
    eadj[idx] = valid ? (__bf16)__expf(a) : (__bf16)0.f;
  }
}

// ---------------- tiled GEMM: C[8192 x N] = A[8192 x K] @ B[N x K]^T ----------------
// 128x128 tile, 4 waves (2x2), each wave 64x64 (4x4 fragments). BK=32.
// NSPLIT>1: K split into NSPLIT slices; slice s writes outf + s*8192*out_ncols.
template<int EPI, int NSPLIT>
__global__ __launch_bounds__(256) void k_gemm(const bf16_t* __restrict__ A,
                                              const bf16_t* __restrict__ B,
                                              int K, int nbx,
                                              const float* __restrict__ bias,
                                              bf16_t* __restrict__ outb,
                                              float* __restrict__ outf,
                                              int out_ncols) {
  __shared__ bf16_t lA[2][4096];
  __shared__ bf16_t lB[2][4096];
  int bid = blockIdx.x;
  int bps = 64 * nbx;                 // blocks per split (M/128 = 64)
  int split = bid / bps, r = bid - split * bps;
  int nb = r % nbx, mb = r / nbx;
  int KS = K / NSPLIT;
  const bf16_t* Ab = A + (size_t)split * KS;
  const bf16_t* Bb = B + (size_t)split * KS;
  int tid = threadIdx.x, wid = tid >> 6, lane = tid & 63;
  int l16 = lane & 15, g = lane >> 4;
  int wr = wid >> 1, wc = wid & 1;
  int rowbase = mb * 128, c0 = nb * 128;

  int dA0 = wid * 2048 + lane * 16;
  int rA0 = dA0 >> 6;
  int cbA = ((dA0 >> 4) & 3) ^ (rA0 & 3);
  const bf16_t* Asrc0 = Ab + (size_t)(rowbase + rA0) * K + cbA * 8;
  const bf16_t* Asrc1 = Ab + (size_t)(rowbase + rA0 + 16) * K + cbA * 8;
  const bf16_t* Bsrc0 = Bb + (size_t)(c0 + rA0) * K + cbA * 8;
  const bf16_t* Bsrc1 = Bb + (size_t)(c0 + rA0 + 16) * K + cbA * 8;

  f32x4 acc[4][4];
#pragma unroll
  for (int m = 0; m < 4; m++)
#pragma unroll
    for (int n = 0; n < 4; n++) acc[m][n] = (f32x4){0.f, 0.f, 0.f, 0.f};

  gload_lds16(Asrc0, (char*)&lA[0][0] + wid * 2048);
  gload_lds16(Asrc1, (char*)&lA[0][0] + wid * 2048 + 1024);
  gload_lds16(Bsrc0, (char*)&lB[0][0] + wid * 2048);
  gload_lds16(Bsrc1, (char*)&lB[0][0] + wid * 2048 + 1024);
  __syncthreads();

  for (int k0 = 0; k0 < KS; k0 += 32) {
    int buf = (k0 >> 5) & 1;
    if (k0 + 32 < KS) {
      gload_lds16(Asrc0 + k0 + 32, (char*)&lA[buf ^ 1][0] + wid * 2048);
      gload_lds16(Asrc1 + k0 + 32, (char*)&lA[buf ^ 1][0] + wid * 2048 + 1024);
      gload_lds16(Bsrc0 + k0 + 32, (char*)&lB[buf ^ 1][0] + wid * 2048);
      gload_lds16(Bsrc1 + k0 + 32, (char*)&lB[buf ^ 1][0] + wid * 2048 + 1024);
    }
    const char* cA = (const char*)&lA[buf][0];
    const char* cB = (const char*)&lB[buf][0];
    bf16x8 af[4], bq[4];
#pragma unroll
    for (int m = 0; m < 4; m++) {
      int row = wr * 64 + m * 16 + l16;
      af[m] = *(const bf16x8*)(cA + row * 64 + ((g ^ (row & 3)) << 4));
    }
#pragma unroll
    for (int n = 0; n < 4; n++) {
      int row = wc * 64 + n * 16 + l16;
      bq[n] = *(const bf16x8*)(cB + row * 64 + ((g ^ (row & 3)) << 4));
    }
#pragma unroll
    for (int m = 0; m < 4; m++)
#pragma unroll
      for (int n = 0; n < 4; n++) acc[m][n] = mfma16(af[m], bq[n], acc[m][n]);
    __syncthreads();
  }

  int which = c0 / out_ncols;
  int cloc0 = c0 - which * out_ncols;
  size_t obase = (size_t)which * 8192 * out_ncols +
                 (size_t)split * 8192 * out_ncols * (NSPLIT > 1 ? 1 : 0);
  float osc = (EPI == 0 && which == 0) ? QSCALE : 1.0f;  // q pre-scale (base-2)
#pragma unroll
  for (int n = 0; n < 4; n++) {
    int col = cloc0 + wc * 64 + n * 16 + l16;
    float bv = (EPI >= 1 && bias && split == 0) ? bias[col] : 0.f;
#pragma unroll
    for (int m = 0; m < 4; m++)
#pragma unroll
      for (int j = 0; j < 4; j++) {
        int row = rowbase + wr * 64 + m * 16 + g * 4 + j;
        float v = acc[m][n][j] + bv;
        size_t idx = obase + (size_t)row * out_ncols + col;
        if (EPI == 1) outb[idx] = (__bf16)fmaxf(v, 0.f);
        else if (EPI == 0) outb[idx] = (__bf16)(v * osc);
        else outf[idx] = v;
      }
  }
}

// ---------------- residual + LayerNorm: sums nsplit f32 partials ----------------
__global__ __launch_bounds__(256) void k_resln(const float* __restrict__ gin,
                                               int nsplit,
                                               const float* __restrict__ residf,
                                               const bf16_t* __restrict__ residb,
                                               const float* __restrict__ gam,
                                               const float* __restrict__ bet,
                                               float* __restrict__ outf,
                                               bf16_t* __restrict__ outb) {
  const size_t GS = (size_t)8192 * 512;
  int row = blockIdx.x * 4 + (threadIdx.x >> 6);
  int lane = threadIdx.x & 63;
  const float* gp = gin + (size_t)row * 512;
  float4 a0 = ((const float4*)gp)[lane];
  float4 a1 = ((const float4*)gp)[lane + 64];
  for (int s = 1; s < nsplit; s++) {
    const float* gp2 = gp + s * GS;
    float4 r0 = ((const float4*)gp2)[lane];
    float4 r1 = ((const float4*)gp2)[lane + 64];
    a0.x += r0.x; a0.y += r0.y; a0.z += r0.z; a0.w += r0.w;
    a1.x += r1.x; a1.y += r1.y; a1.z += r1.z; a1.w += r1.w;
  }
  if (residf) {
    const float* rp = residf + (size_t)row * 512;
    float4 r0 = ((const float4*)rp)[lane];
    float4 r1 = ((const float4*)rp)[lane + 64];
    a0.x += r0.x; a0.y += r0.y; a0.z += r0.z; a0.w += r0.w;
    a1.x += r1.x; a1.y += r1.y; a1.z += r1.z; a1.w += r1.w;
  } else {
    const bf16_t* rp = residb + (size_t)row * 512;
    bf16x4 r0 = ((const bf16x4*)rp)[lane];
    bf16x4 r1 = ((const bf16x4*)rp)[lane + 64];
    a0.x += (float)r0[0]; a0.y += (float)r0[1]; a0.z += (float)r0[2]; a0.w += (float)r0[3];
    a1.x += (float)r1[0]; a1.y += (float)r1[1]; a1.z += (float)r1[2]; a1.w += (float)r1[3];
  }
  float s = a0.x + a0.y + a0.z + a0.w + a1.x + a1.y + a1.z + a1.w;
  for (int off = 1; off < 64; off <<= 1) s += __shfl_xor(s, off);
  float mu = s * (1.f / 512.f);
  float sq = (a0.x - mu) * (a0.x - mu) + (a0.y - mu) * (a0.y - mu) +
             (a0.z - mu) * (a0.z - mu) + (a0.w - mu) * (a0.w - mu) +
             (a1.x - mu) * (a1.x - mu) + (a1.y - mu) * (a1.y - mu) +
             (a1.z - mu) * (a1.z - mu) + (a1.w - mu) * (a1.w - mu);
  for (int off = 1; off < 64; off <<= 1) sq += __shfl_xor(sq, off);
  float rs = rsqrtf(sq * (1.f / 512.f) + EPSC);

  float4 g0 = ((const float4*)gam)[lane], g1v = ((const float4*)gam)[lane + 64];
  float4 b0 = ((const float4*)bet)[lane], b1v = ((const float4*)bet)[lane + 64];
  float4 o0, o1;
  o0.x = (a0.x - mu) * rs * g0.x + b0.x;  o0.y = (a0.y - mu) * rs * g0.y + b0.y;
  o0.z = (a0.z - mu) * rs * g0.z + b0.z;  o0.w = (a0.w - mu) * rs * g0.w + b0.w;
  o1.x = (a1.x - mu) * rs * g1v.x + b1v.x; o1.y = (a1.y - mu) * rs * g1v.y + b1v.y;
  o1.z = (a1.z - mu) * rs * g1v.z + b1v.z; o1.w = (a1.w - mu) * rs * g1v.w + b1v.w;
  if (outf) {
    float* op = outf + (size_t)row * 512;
    ((float4*)op)[lane] = o0;
    ((float4*)op)[lane + 64] = o1;
  }
  if (outb) {
    bf16_t* op = outb + (size_t)row * 512;
    bf16x4 q0 = { (__bf16)o0.x, (__bf16)o0.y, (__bf16)o0.z, (__bf16)o0.w };
    bf16x4 q1 = { (__bf16)o1.x, (__bf16)o1.y, (__bf16)o1.z, (__bf16)o1.w };
    ((bf16x4*)op)[lane] = q0;
    ((bf16x4*)op)[lane + 64] = q1;
  }
}

// ---------------- v transpose (blk<1024) + kmax (blk>=1024) ----------------
__global__ __launch_bounds__(256) void k_vtrans_knorm(const bf16_t* __restrict__ v,
                                                      bf16_t* __restrict__ vT,
                                                      const bf16_t* __restrict__ kk,
                                                      float* __restrict__ kmax) {
  __shared__ bf16_t t[64 * 66];
  __shared__ float red[4];
  int bid = blockIdx.x;
  int tid = threadIdx.x, wid = tid >> 6, lane = tid & 63;
  if (bid < 1024) {
    int nt = bid & 15, h = (bid >> 4) & 7, b = bid >> 7;
    for (int i = 0; i < 16; i++) {
      int n = wid * 16 + i;
      t[lane * 66 + n] = v[(size_t)(b * 1024 + nt * 64 + n) * 512 + h * 64 + lane];
    }
    __syncthreads();
    for (int i = 0; i < 16; i++) {
      int d = wid * 16 + i;
      vT[(size_t)((b * 8 + h) * 64 + d) * 1024 + nt * 64 + lane] = t[d * 66 + lane];
    }
  } else {
    int bh = bid - 1024;
    int b = bh >> 3, h = bh & 7;
    float mx = 0.f;
    for (int n = tid; n < 1024; n += 256) {
      const bf16_t* kp = kk + (size_t)(b * 1024 + n) * 512 + h * 64;
      float ss = 0.f;
#pragma unroll
      for (int vv = 0; vv < 8; vv++) {
        bf16x8 kv = *(const bf16x8*)(kp + vv * 8);
#pragma unroll
        for (int e = 0; e < 8; e++) { float f = (float)kv[e]; ss += f * f; }
      }
      mx = fmaxf(mx, ss);
    }
    for (int off = 1; off < 64; off <<= 1) mx = fmaxf(mx, __shfl_xor(mx, off));
    if (lane == 0) red[wid] = mx;
    __syncthreads();
    if (tid == 0) kmax[bh] = sqrtf(fmaxf(fmaxf(red[0], red[1]), fmaxf(red[2], red[3])));
  }
}

// ---------------- attention: ctx (normalized) + crl = C + log2(l) ----------------
// grid 512: bid = qt*64 + (h + 8b). Block: 512 threads (8 waves x 16 q = 128 q),
// full k = 16 tiles of 64. C = |q'|*kmax computed in-register from aq frags.
__global__ __launch_bounds__(512) void k_attn_ctx(const bf16_t* __restrict__ q,
                                                  const bf16_t* __restrict__ kk,
                                                  const bf16_t* __restrict__ vT,
                                                  const bf16_t* __restrict__ eadj,
                                                  const float* __restrict__ kmax,
                                                  bf16_t* __restrict__ ctx,
                                                  float* __restrict__ crl) {
  __shared__ bf16_t ldsK[2][4096];
  __shared__ bf16_t ldsV[2][4096];
  __shared__ bf16_t pt[8][16 * 68];
  int bid = blockIdx.x;
  int qt = bid >> 6, h = bid & 7, b = (bid >> 3) & 7;
  int tid = threadIdx.x, wid = tid >> 6, lane = tid & 63;
  int l16 = lane & 15, g = lane >> 4;
  int qg0 = qt * 128 + wid * 16;
  int kvbase = (b * 8 + h) * 64;

  int d0 = wid * 1024 + lane * 16;
  int row0 = d0 >> 7;
  int cb0 = ((d0 >> 4) & 7) ^ (row0 & 7);
  const bf16_t* ksrc = kk + (size_t)(b * 1024) * 512 + h * 64;
  const bf16_t* vsrc = vT + (size_t)kvbase * 1024;

  auto stage = [&](int buf, int kc0) {
    gload_lds16(ksrc + (size_t)(kc0 + row0) * 512 + cb0 * 8, &ldsK[buf][wid * 512]);
    gload_lds16(vsrc + (size_t)row0 * 1024 + kc0 + cb0 * 8, &ldsV[buf][wid * 512]);
  };

  const bf16_t* qp = q + (size_t)(b * 1024 + qg0 + l16) * 512 + h * 64 + 8 * g;
  bf16x8 aq0 = *(const bf16x8*)qp;
  bf16x8 aq1 = *(const bf16x8*)(qp + 32);

  // C = |q'| * kmax, computed from fragments: lane(l16,g) holds 16 elems of row l16
  float kmaxv = kmax[b * 8 + h];
  float ssq = 0.f;
#pragma unroll
  for (int e = 0; e < 8; e++) {
    float f0 = (float)aq0[e], f1 = (float)aq1[e];
    ssq += f0 * f0 + f1 * f1;
  }
  ssq += __shfl_xor(ssq, 16);
  ssq += __shfl_xor(ssq, 32);
  float Cn = sqrtf(ssq) * kmaxv;   // lane i holds row (i&15)'s bound
  float Cj[4];
#pragma unroll
  for (int j = 0; j < 4; j++) Cj[j] = __shfl(Cn, g * 4 + j);

  f32x4 cacc[4];
#pragma unroll
  for (int d = 0; d < 4; d++) cacc[d] = (f32x4){0.f, 0.f, 0.f, 0.f};
  float ls[4] = {0.f, 0.f, 0.f, 0.f};
  bf16_t* myp = pt[wid];
  int rph = l16 & 7;
  const bf16_t* erow = eadj + (size_t)(qg0 + g * 4) * 1024 + l16;

  bf16_t eaA[4][4], eaB[4][4];
  stage(0, 0);
#pragma unroll
  for (int cg = 0; cg < 4; cg++)
#pragma unroll
    for (int j = 0; j < 4; j++) eaA[cg][j] = erow[(size_t)j * 1024 + cg * 16];
  __syncthreads();

  auto tile = [&](int kt, int buf, bf16_t (&eaC)[4][4], bf16_t (&eaN)[4][4]) {
    int kc0 = kt * 64;
    int ktn = (kt + 1 < 16) ? kt + 1 : 15;
    stage(buf ^ 1, ktn * 64);
#pragma unroll
    for (int cg = 0; cg < 4; cg++)
#pragma unroll
      for (int j = 0; j < 4; j++)
        eaN[cg][j] = erow[(size_t)j * 1024 + ktn * 64 + cg * 16];

    const char* curK = (const char*)ldsK[buf];
    const char* curV = (const char*)ldsV[buf];

#pragma unroll
    for (int cg = 0; cg < 4; cg++) {
      const char* krow = curK + ((cg * 16 + l16) << 7);
      bf16x8 k0 = *(const bf16x8*)(krow + ((g ^ rph) << 4));
      bf16x8 k1 = *(const bf16x8*)(krow + (((g + 4) ^ rph) << 4));
      f32x4 s = (f32x4){0.f, 0.f, 0.f, 0.f};
      __builtin_amdgcn_s_setprio(1);
      s = mfma16(aq0, k0, s);
      s = mfma16(aq1, k1, s);
      __builtin_amdgcn_s_setprio(0);
#pragma unroll
      for (int j = 0; j < 4; j++) {
        float p = (float)eaC[cg][j] * exp2f(s[j] - Cj[j]);
        ls[j] += p;
        myp[(g * 4 + j) * 68 + cg * 16 + l16] = (__bf16)p;
      }
    }
#pragma unroll
    for (int half = 0; half < 2; half++) {
      bf16x8 pa = *(const bf16x8*)(myp + l16 * 68 + half * 32 + 8 * g);
      __builtin_amdgcn_s_setprio(1);
#pragma unroll
      for (int dg = 0; dg < 4; dg++) {
        const char* vrow = curV + ((dg * 16 + l16) << 7);
        bf16x8 vv = *(const bf16x8*)(vrow + (((g + half * 4) ^ rph) << 4));
        cacc[dg] = mfma16(pa, vv, cacc[dg]);
      }
      __builtin_amdgcn_s_setprio(0);
    }
    __syncthreads();
  };

  for (int k2 = 0; k2 < 8; k2++) {
    tile(2 * k2,     0, eaA, eaB);
    tile(2 * k2 + 1, 1, eaB, eaA);
  }

#pragma unroll
  for (int j = 0; j < 4; j++)
    for (int off = 1; off < 16; off <<= 1) ls[j] += __shfl_xor(ls[j], off);
  float rc[4];
#pragma unroll
  for (int j = 0; j < 4; j++) rc[j] = (ls[j] > 0.f) ? (1.f / ls[j]) : 0.f;

#pragma unroll
  for (int dg = 0; dg < 4; dg++)
#pragma unroll
    for (int j = 0; j < 4; j++) {
      int row = qg0 + g * 4 + j;
      ctx[(size_t)(b * 1024 + row) * 512 + h * 64 + dg * 16 + l16] =
          (__bf16)(cacc[dg][j] * rc[j]);
    }
  if (l16 == 0) {
#pragma unroll
    for (int j = 0; j < 4; j++) {
      int li = (b * 8 + h) * 1024 + qg0 + g * 4 + j;
      crl[li] = (ls[j] > 0.f) ? (Cj[j] + __log2f(ls[j])) : 1.0e30f;
    }
  }
}

// ---------------- attention mean over heads -> mout (barrier-free) ----------------
__global__ __launch_bounds__(256, 4) void k_attn_mean(const bf16_t* __restrict__ q,
                                                      const bf16_t* __restrict__ kk,
                                                      const bf16_t* __restrict__ eadj,
                                                      const float* __restrict__ crl,
                                                      float* __restrict__ mout) {
  __shared__ bf16_t lds[4][2][2048];   // [wave][buf][4KB]
  int bid = blockIdx.x;
  int kq = bid & 7, qt = (bid >> 3) & 15, b = bid >> 7;
  int tid = threadIdx.x, wid = tid >> 6, lane = tid & 63;
  int l16 = lane & 15, g = lane >> 4;
  int qg0 = qt * 64 + wid * 16;
  int kbase = kq * 128;
  int rl = lane >> 3;
  int cb = (lane & 7) ^ rl;
  const bf16_t* ksrc = kk + (size_t)(b * 1024 + kbase) * 512;

  auto stage = [&](int t) {
    int h = t >> 2, c = t & 3;
    char* dst = (char*)&lds[wid][t & 1][0];
    const bf16_t* sp = ksrc + (size_t)(c * 32 + rl) * 512 + h * 64 + cb * 8;
#pragma unroll
    for (int i = 0; i < 4; i++)
      gload_lds16(sp + (size_t)i * 8 * 512, dst + i * 1024);
  };

  f32x4 macc[8];
#pragma unroll
  for (int kg = 0; kg < 8; kg++) macc[kg] = (f32x4){0.f, 0.f, 0.f, 0.f};

  stage(0);

  for (int h = 0; h < 8; h++) {
    const bf16_t* qp = q + (size_t)(b * 1024 + qg0 + l16) * 512 + h * 64 + 8 * g;
    bf16x8 aq0 = *(const bf16x8*)qp;
    bf16x8 aq1 = *(const bf16x8*)(qp + 32);
    f32x4 CR = *(const f32x4*)(crl + (b * 8 + h) * 1024 + qg0 + g * 4);
#pragma unroll
    for (int c = 0; c < 4; c++) {
      int t = h * 4 + c;
      __builtin_amdgcn_sched_barrier(0);
      if (t < 31) {
        stage(t + 1);
        __builtin_amdgcn_sched_barrier(0);
        asm volatile("s_waitcnt vmcnt(4)" ::: "memory");
      } else {
        asm volatile("s_waitcnt vmcnt(0)" ::: "memory");
      }
      __builtin_amdgcn_sched_barrier(0);
      const char* cK = (const char*)&lds[wid][t & 1][0];
#pragma unroll
      for (int cg = 0; cg < 2; cg++) {
        const char* krow = cK + ((cg * 16 + l16) << 7);
        bf16x8 k0 = *(const bf16x8*)(krow + ((g ^ (l16 & 7)) << 4));
        bf16x8 k1 = *(const bf16x8*)(krow + (((g + 4) ^ (l16 & 7)) << 4));
        f32x4 s = (f32x4){0.f, 0.f, 0.f, 0.f};
        __builtin_amdgcn_s_setprio(1);
        s = mfma16(aq0, k0, s);
        s = mfma16(aq1, k1, s);
        __builtin_amdgcn_s_setprio(0);
        int kg = c * 2 + cg;
#pragma unroll
        for (int j = 0; j < 4; j++)
          macc[kg][j] += exp2f(s[j] - CR[j]);
      }
    }
  }

#pragma unroll
  for (int kg = 0; kg < 8; kg++)
#pragma unroll
    for (int j = 0; j < 4; j++) {
      size_t off = (size_t)(qg0 + g * 4 + j) * 1024 + kbase + kg * 16 + l16;
      mout[(size_t)b * 1048576 + off] = macc[kg][j] * (float)eadj[off] * 0.125f;
    }
}

extern "C" void kernel_launch(void* const* d_in, const int* in_sizes, int n_in,
                              void* d_out, int out_size, void* d_ws, size_t ws_size,
                              hipStream_t stream) {
  (void)in_sizes; (void)n_in; (void)out_size; (void)ws_size;
  const float* x   = (const float*)d_in[0];
  const float* adj = (const float*)d_in[1];
  const int*   msk = (const int*)d_in[2];
  const float* Wq  = (const float*)d_in[3];
  const float* Wk  = (const float*)d_in[4];
  const float* Wv  = (const float*)d_in[5];
  const float* Wo  = (const float*)d_in[6];
  const float* W1  = (const float*)d_in[7];
  const float* b1  = (const float*)d_in[8];
  const float* W2  = (const float*)d_in[9];
  const float* b2  = (const float*)d_in[10];
  const float* g1  = (const float*)d_in[11];
  const float* be1 = (const float*)d_in[12];
  const float* g2  = (const float*)d_in[13];
  const float* be2 = (const float*)d_in[14];

  float* out  = (float*)d_out;
  float* mout = out + (size_t)8 * 1024 * 512;

  char* ws = (char*)d_ws;
  const size_t MB = 1024 * 1024;
  bf16_t* wqb = (bf16_t*)(ws);
  bf16_t* wkb = (bf16_t*)(ws + 512 * 1024);
  bf16_t* wvb = (bf16_t*)(ws + 1 * MB);
  bf16_t* wob = (bf16_t*)(ws + 3 * MB / 2);
  bf16_t* w1b = (bf16_t*)(ws + 2 * MB);
  bf16_t* w2b = (bf16_t*)(ws + 4 * MB);
  float*  crl  = (float*)(ws + 6 * MB + 256 * 1024); // 256 KB (C + log2 l)
  float*  kmax = (float*)(ws + 6 * MB + 768 * 1024); // 256 B
  bf16_t* xb   = (bf16_t*)(ws + 8 * MB);   // 8-16: x bf16; then ctx; then zb
  bf16_t* ctx  = xb;
  bf16_t* zb   = xb;
  bf16_t* qb   = (bf16_t*)(ws + 16 * MB);  // 16-24 (dead after attn_mean)
  bf16_t* kb   = (bf16_t*)(ws + 24 * MB);  // 24-32 (dead after attn_mean)
  bf16_t* vb   = (bf16_t*)(ws + 32 * MB);  // 32-40 (dead after vtrans)
  bf16_t* vT   = (bf16_t*)(ws + 40 * MB);  // 40-48 (dead after attn_ctx)
  float*  gout1 = (float*)(ws + 16 * MB);  // 16-48: 2x16MB f32 (wo split-K partials)
  bf16_t* hb    = (bf16_t*)(ws + 16 * MB); // 16-48 bf16 (ffn1 -> ffn2)
  float*  gout2 = (float*)(ws + 44 * MB);  // 44-76: 2x16MB f32 (ffn2 split-K partials)
  bf16_t* eadj  = (bf16_t*)(ws + 72 * MB); // 72-74 (dead before ffn2 partials land?
  // NOTE: eadj (72-74) overlaps gout2 split1 (60-76). eadj is dead after
  // attn_mean, which completes before the ffn2 gemm writes gout2. Safe.

  // converts (x + all weights, one launch)
  k_cvtall<<<7168, 256, 0, stream>>>(x, Wq, Wk, Wv, Wo, W1, W2,
                                     xb, wqb, wkb, wvb, wob, w1b, w2b);

  k_prep<<<256, 256, 0, stream>>>(adj, msk, eadj);

  // QKV: one GEMM, N=1536 (wq|wk|wv contiguous); q pre-scaled by 0.125*log2e
  k_gemm<0, 1><<<64 * 12, 256, 0, stream>>>(xb, wqb, 512, 12, nullptr, qb, nullptr, 512);
  // v transpose + kmax in one launch
  k_vtrans_knorm<<<1088, 256, 0, stream>>>(vb, vT, kb, kmax);

  // attention: ctx (normalized, full-k, 512-thr blocks, in-register C) + crl, then mean
  k_attn_ctx<<<512, 512, 0, stream>>>(qb, kb, vT, eadj, kmax, ctx, crl);
  k_attn_mean<<<1024, 256, 0, stream>>>(qb, kb, eadj, crl, mout);

  // Wo proj (split-K x2) -> gout1[2]; residual(x f32) + LN1 -> zb (bf16)
  k_gemm<2, 2><<<2 * 64 * 4, 256, 0, stream>>>(ctx, wob, 512, 4, nullptr, nullptr, gout1, 512);
  k_resln<<<2048, 256, 0, stream>>>(gout1, 2, x, nullptr, g1, be1, nullptr, zb);
  // FFN1: relu(zb @ W1^T + b1) -> hb
  k_gemm<1, 1><<<64 * 16, 256, 0, stream>>>(zb, w1b, 512, 16, b1, hb, nullptr, 2048);
  // FFN2 (split-K x2) -> gout2[2]; residual(zb bf16) + LN2 -> out
  k_gemm<2, 2><<<2 * 64 * 4, 256, 0, stream>>>(hb, w2b, 2048, 4, b2, nullptr, gout2, 512);
  k_resln<<<2048, 256, 0, stream>>>(gout2, 2, nullptr, zb, g2, be2, out, nullptr);
}